// Round 13
// baseline (863.039 us; speedup 1.0000x reference)
//
#include <hip/hip_runtime.h>

#define TM 16

typedef float v2f __attribute__((ext_vector_type(2)));

// bf16 helpers (xl staged in bf16 to halve gather traffic)
__device__ __forceinline__ v2f unpack2(unsigned u) {
    union { unsigned u; float f; } lo, hi;
    lo.u = u << 16;
    hi.u = u & 0xffff0000u;
    v2f r;
    r.x = lo.f;
    r.y = hi.f;
    return r;
}
// fp32 -> bf16 (round to nearest even)
__device__ __forceinline__ unsigned short f2b(float f) {
    union { float f; unsigned u; } c;
    c.f = f;
    unsigned r = c.u + 0x7fffu + ((c.u >> 16) & 1u);
    return (unsigned short)(r >> 16);
}

// edge dtype: int64 iff the 16 sampled high words are all zero (uniform
// scalar loads, evaluated per-block).
__device__ __forceinline__ int edges_are_i64(const unsigned int* raw) {
    int f = 1;
#pragma unroll
    for (int k = 0; k < 16; ++k) f = f && (raw[2 * k + 1] == 0u);
    return f;
}
__device__ __forceinline__ int edge_at(const unsigned int* raw, int f,
                                       size_t idx) {
    return f ? (int)raw[2 * idx] : (int)raw[idx];
}

// ---------------------------------------------------------------------------
// K1: xl = x@W_l+b_l (-> bf16), xr = x@W_r+b_r (-> fp32). (Nx64)@(64x256).
// 16 nodes per 256-thread block; x-tile in LDS; thread j owns column j.
// FUSED: degree histogram (independent work) appended as a grid-stride tail
// -- removes one 850K-edge dispatch and overlaps atomics with FMA phase.
// ---------------------------------------------------------------------------
__global__ __launch_bounds__(256) void k_proj(
    const float* __restrict__ x, const float* __restrict__ Wl,
    const float* __restrict__ bl, const float* __restrict__ Wr,
    const float* __restrict__ br, unsigned short* __restrict__ xl,
    float* __restrict__ xr, int N,
    const unsigned int* __restrict__ eraw, int* __restrict__ deg, int E,
    int Etot) {
    __shared__ float xs[64][TM + 4];
    const int tid = threadIdx.x;
    const int base = blockIdx.x * TM;
    for (int t = tid; t < TM * 64; t += 256) {
        int m = t >> 6, k = t & 63;
        int n = base + m;
        xs[k][m] = (n < N) ? x[(size_t)n * 64 + k] : 0.f;
    }
    __syncthreads();
    const int j = tid;  // output column 0..255
    v2f accl2[TM / 2], accr2[TM / 2];
    const float blj = bl[j], brj = br[j];
#pragma unroll
    for (int m = 0; m < TM / 2; ++m) {
        accl2[m].x = blj; accl2[m].y = blj;
        accr2[m].x = brj; accr2[m].y = brj;
    }
    for (int k = 0; k < 64; ++k) {
        const float wl = Wl[(size_t)k * 256 + j];
        const float wr = Wr[(size_t)k * 256 + j];
        v2f wl2, wr2;
        wl2.x = wl; wl2.y = wl;
        wr2.x = wr; wr2.y = wr;
        const float4* xrow = (const float4*)(&xs[k][0]);
#pragma unroll
        for (int mm = 0; mm < TM / 4; ++mm) {
            float4 xv = xrow[mm];
            v2f x01, x23;
            x01.x = xv.x; x01.y = xv.y;
            x23.x = xv.z; x23.y = xv.w;
            accl2[2 * mm]     = __builtin_elementwise_fma(x01, wl2, accl2[2 * mm]);
            accl2[2 * mm + 1] = __builtin_elementwise_fma(x23, wl2, accl2[2 * mm + 1]);
            accr2[2 * mm]     = __builtin_elementwise_fma(x01, wr2, accr2[2 * mm]);
            accr2[2 * mm + 1] = __builtin_elementwise_fma(x23, wr2, accr2[2 * mm + 1]);
        }
    }
#pragma unroll
    for (int m = 0; m < TM; ++m) {
        int n = base + m;
        if (n < N) {
            float vl = (m & 1) ? accl2[m >> 1].y : accl2[m >> 1].x;
            float vr = (m & 1) ? accr2[m >> 1].y : accr2[m >> 1].x;
            xl[(size_t)n * 256 + j] = f2b(vl);
            xr[(size_t)n * 256 + j] = vr;
        }
    }
    // fused histogram tail
    const int f = edges_are_i64(eraw);
    const int stride = gridDim.x * 256;
    for (int e = blockIdx.x * 256 + tid; e < Etot; e += stride) {
        int d = (e < E) ? edge_at(eraw, f, (size_t)E + e) : (e - E);
        if ((unsigned)d >= (unsigned)N) d = 0;  // defensive clamp
        atomicAdd(&deg[d], 1);
    }
}

// ---------------------------------------------------------------------------
// CSR build: parallel 2-kernel scan (196 blocks each) -> scatter via cursor.
// ---------------------------------------------------------------------------
__global__ void k_scanA(const int* __restrict__ deg, int* __restrict__ bsum,
                        int N) {
    __shared__ int s[256];
    int t = threadIdx.x;
    int i = blockIdx.x * 256 + t;
    s[t] = (i < N) ? deg[i] : 0;
    __syncthreads();
    for (int d = 128; d > 0; d >>= 1) {
        if (t < d) s[t] += s[t + d];
        __syncthreads();
    }
    if (t == 0) bsum[blockIdx.x] = s[0];
}

// fused: each block computes its global offset (masked reduce over bsum,
// NB <= 256) then the exclusive scan of its own 256 deg entries.
// Writes BOTH row_start and cursor (scatter consumes cursor atomically).
__global__ void k_scanC(const int* __restrict__ deg,
                        const int* __restrict__ bsum,
                        int* __restrict__ row_start, int* __restrict__ cursor,
                        int Etot, int N) {
    __shared__ int s[256];
    __shared__ int off_s;
    const int t = threadIdx.x;
    s[t] = (t < blockIdx.x) ? bsum[t] : 0;
    __syncthreads();
    for (int d = 128; d > 0; d >>= 1) {
        if (t < d) s[t] += s[t + d];
        __syncthreads();
    }
    if (t == 0) off_s = s[0];
    __syncthreads();
    const int offset = off_s;
    __syncthreads();
    const int i = blockIdx.x * 256 + t;
    const int v = (i < N) ? deg[i] : 0;
    s[t] = v;
    __syncthreads();
    for (int d = 1; d < 256; d <<= 1) {
        int add = (t >= d) ? s[t - d] : 0;
        __syncthreads();
        s[t] += add;
        __syncthreads();
    }
    if (i < N) {
        int rs = s[t] - v + offset;
        row_start[i] = rs;
        cursor[i] = rs;
    }
    if (blockIdx.x == gridDim.x - 1 && t == 0) row_start[N] = Etot;
}

__global__ void k_scatter(const unsigned int* __restrict__ raw,
                          int* __restrict__ cursor, int* __restrict__ csr_src,
                          int E, int Etot, int N) {
    int e = blockIdx.x * 256 + threadIdx.x;
    if (e >= Etot) return;
    int f = edges_are_i64(raw);
    int s, d;
    if (e < E) {
        s = edge_at(raw, f, (size_t)e);
        d = edge_at(raw, f, (size_t)E + e);
    } else {
        s = d = e - E;
    }
    if ((unsigned)s >= (unsigned)N) s = 0;  // defensive clamp
    if ((unsigned)d >= (unsigned)N) d = 0;
    int slot = atomicAdd(&cursor[d], 1);
    if ((unsigned)slot < (unsigned)Etot) csr_src[slot] = s;
    // slots are a permutation of [0,Etot): every slot written, value < N.
}

// ---------------------------------------------------------------------------
// K3: per-node softmax-aggregate. PERSISTENT WAVES + work-queue ticket:
// one node per wave at a time, next node via atomicAdd -- removes the
// block-granular load imbalance that made r12's VALU time ~2.5x the static
// instruction count (Poisson(17) degrees; block held by slowest of 4 waves).
// Per node: two edges per pass (half = lane>>5; sub-lane owns 8 channels of
// one head; uint4 bf16 gather), rotating D=3 pipeline, packed-float2 math.
// ---------------------------------------------------------------------------
__global__ __launch_bounds__(256) void k_aggregate(
    const unsigned short* __restrict__ xl, const float* __restrict__ xr,
    const float* __restrict__ att, const float* __restrict__ bias,
    const int* __restrict__ row_start, const int* __restrict__ csr_src,
    float* __restrict__ out, int* __restrict__ ticket, int N) {
    const int lane = threadIdx.x & 63;
    const int half = lane >> 5;  // which edge of the pair
    const int sl = lane & 31;    // channels [sl*8, sl*8+8) of the 256-row
    const int co = sl * 8;
    const unsigned short* xlo = xl + co;  // lane-constant base

    v2f av[4];
    {
        const float4 a0 = *(const float4*)(att + co);
        const float4 a1 = *(const float4*)(att + co + 4);
        av[0].x = a0.x; av[0].y = a0.y;
        av[1].x = a0.z; av[1].y = a0.w;
        av[2].x = a1.x; av[2].y = a1.y;
        av[3].x = a1.z; av[3].y = a1.w;
    }

    for (;;) {
        int i;
        if (lane == 0) i = atomicAdd(ticket, 1);
        i = __shfl(i, 0);
        if (i >= N) return;

        v2f xrv[4];
        {
            const float4 x0 = *(const float4*)(xr + (size_t)i * 256 + co);
            const float4 x1 = *(const float4*)(xr + (size_t)i * 256 + co + 4);
            xrv[0].x = x0.x; xrv[0].y = x0.y;
            xrv[1].x = x0.z; xrv[1].y = x0.w;
            xrv[2].x = x1.x; xrv[2].y = x1.y;
            xrv[3].x = x1.z; xrv[3].y = x1.w;
        }
        v2f accv[4];
#pragma unroll
        for (int p = 0; p < 4; ++p) { accv[p].x = 0.f; accv[p].y = 0.f; }
        float den = 0.f;
        const int beg = row_start[i];
        const int end = row_start[i + 1];  // deg >= 1 (self loop)
        const int last = end - 1;

        constexpr int D = 3;  // pair-slots in flight (6 edges)
        uint4 cur[D];
        int sidx[D];
#pragma unroll
        for (int d = 0; d < D; ++d) {
            int s = csr_src[min(beg + 2 * d + half, last)];
            cur[d] = *(const uint4*)(xlo + (size_t)s * 256);
        }
#pragma unroll
        for (int d = 0; d < D; ++d)
            sidx[d] = csr_src[min(beg + 2 * D + 2 * d + half, last)];

        for (int e = beg; e < end; e += 2 * D) {
#pragma unroll
            for (int d = 0; d < D; ++d) {
                const uint4 cu = cur[d];
                // rotate: refill this slot for edge e+2D+2d+half
                cur[d] = *(const uint4*)(xlo + (size_t)sidx[d] * 256);
                sidx[d] = csr_src[min(e + 4 * D + 2 * d + half, last)];

                v2f c0 = unpack2(cu.x), c1 = unpack2(cu.y);
                v2f c2 = unpack2(cu.z), c3 = unpack2(cu.w);
                v2f v0 = c0 + xrv[0], v1 = c1 + xrv[1];
                v2f v2 = c2 + xrv[2], v3 = c3 + xrv[3];
                v0 = __builtin_elementwise_max(v0, v0 * 0.2f);  // leaky relu
                v1 = __builtin_elementwise_max(v1, v1 * 0.2f);
                v2 = __builtin_elementwise_max(v2, v2 * 0.2f);
                v3 = __builtin_elementwise_max(v3, v3 * 0.2f);
                v2f t2a = av[0] * v0;
                v2f t2b = av[1] * v1;
                t2a = __builtin_elementwise_fma(av[2], v2, t2a);
                t2b = __builtin_elementwise_fma(av[3], v3, t2b);
                t2a += t2b;
                float t = t2a.x + t2a.y;
                t += __shfl_xor(t, 1);
                t += __shfl_xor(t, 2);
                t += __shfl_xor(t, 4);  // head dot complete (8 lanes/head)
                float w = __expf(fminf(t, 60.f));
                w = (e + 2 * d + half <= last) ? w : 0.f;  // tail mask
                den += w;
                v2f w2;
                w2.x = w; w2.y = w;
                accv[0] = __builtin_elementwise_fma(w2, c0, accv[0]);
                accv[1] = __builtin_elementwise_fma(w2, c1, accv[1]);
                accv[2] = __builtin_elementwise_fma(w2, c2, accv[2]);
                accv[3] = __builtin_elementwise_fma(w2, c3, accv[3]);
            }
        }
        // combine the two edge-parity halves
        den += __shfl_xor(den, 32);
        float r[8];
        r[0] = accv[0].x; r[1] = accv[0].y; r[2] = accv[1].x; r[3] = accv[1].y;
        r[4] = accv[2].x; r[5] = accv[2].y; r[6] = accv[3].x; r[7] = accv[3].y;
#pragma unroll
        for (int j = 0; j < 8; ++j) r[j] += __shfl_xor(r[j], 32);
        const float inv = 1.f / den;
#pragma unroll
        for (int j = 0; j < 8; ++j) r[j] *= inv;
        // mean over heads: heads occupy sub-lane groups of 8
#pragma unroll
        for (int j = 0; j < 8; ++j) {
            r[j] += __shfl_xor(r[j], 8);
            r[j] += __shfl_xor(r[j], 16);
        }
        if (lane < 8) {
            const float4 b0 = *(const float4*)(bias + lane * 8);
            const float4 b1 = *(const float4*)(bias + lane * 8 + 4);
            *(float4*)(out + (size_t)i * 64 + lane * 8) =
                make_float4(b0.x + 0.25f * r[0], b0.y + 0.25f * r[1],
                            b0.z + 0.25f * r[2], b0.w + 0.25f * r[3]);
            *(float4*)(out + (size_t)i * 64 + lane * 8 + 4) =
                make_float4(b1.x + 0.25f * r[4], b1.y + 0.25f * r[5],
                            b1.z + 0.25f * r[6], b1.w + 0.25f * r[7]);
        }
    }
}

// ---------------------------------------------------------------------------
extern "C" void kernel_launch(void* const* d_in, const int* in_sizes, int n_in,
                              void* d_out, int out_size, void* d_ws,
                              size_t ws_size, hipStream_t stream) {
    const float* x    = (const float*)d_in[0];
    const float* Wl   = (const float*)d_in[1];
    const float* bl   = (const float*)d_in[2];
    const float* Wr   = (const float*)d_in[3];
    const float* br   = (const float*)d_in[4];
    const float* att  = (const float*)d_in[5];
    const float* bias = (const float*)d_in[6];
    const unsigned int* edges_raw = (const unsigned int*)d_in[7];

    const int N = in_sizes[0] / 64;
    const int E = in_sizes[7] / 2;
    const int Etot = E + N;

    // workspace layout (~81 MB; evidenced safe r2/r5/r7-r12)
    char* p = (char*)d_ws;
    size_t off = 0;
    auto carve = [&](size_t bytes) -> char* {
        char* r = p + off;
        off = (off + bytes + 255) & ~(size_t)255;
        return r;
    };
    unsigned short* xl = (unsigned short*)carve((size_t)N * 256 * 2);  // 25.6 MB
    float* xr      = (float*)carve((size_t)N * 256 * 4);               // 51.2 MB
    int* csr_src   = (int*)carve((size_t)Etot * 4);                    // 3.4 MB
    int* row_start = (int*)carve((size_t)(N + 1) * 4);
    int* deg       = (int*)carve((size_t)(N + 64) * 4);  // deg | ticket
    int* ticket    = deg + N;
    int* cursor    = (int*)carve((size_t)N * 4);  // fully written by scanC
    int* bsum      = (int*)carve(1024 * 4);

    hipMemsetAsync(deg, 0, (size_t)(N + 64) * 4, stream);  // deg + ticket

    k_proj<<<(N + TM - 1) / TM, 256, 0, stream>>>(x, Wl, bl, Wr, br, xl, xr, N,
                                                  edges_raw, deg, E, Etot);
    const int NB = (N + 255) / 256;  // 196 <= 256: bsum prefix fits one block
    k_scanA<<<NB, 256, 0, stream>>>(deg, bsum, N);
    k_scanC<<<NB, 256, 0, stream>>>(deg, bsum, row_start, cursor, Etot, N);
    k_scatter<<<(Etot + 255) / 256, 256, 0, stream>>>(edges_raw, cursor,
                                                      csr_src, E, Etot, N);
    k_aggregate<<<2048, 256, 0, stream>>>(xl, xr, att, bias, row_start,
                                          csr_src, (float*)d_out, ticket, N);
}

// Round 14
// 265.320 us; speedup vs baseline: 3.2528x; 3.2528x over previous
//
#include <hip/hip_runtime.h>

#define TM 16

typedef float v2f __attribute__((ext_vector_type(2)));

// bf16 helpers (xl staged in bf16 to halve gather traffic)
__device__ __forceinline__ v2f unpack2(unsigned u) {
    union { unsigned u; float f; } lo, hi;
    lo.u = u << 16;
    hi.u = u & 0xffff0000u;
    v2f r;
    r.x = lo.f;
    r.y = hi.f;
    return r;
}
// fp32 -> bf16 (round to nearest even)
__device__ __forceinline__ unsigned short f2b(float f) {
    union { float f; unsigned u; } c;
    c.f = f;
    unsigned r = c.u + 0x7fffu + ((c.u >> 16) & 1u);
    return (unsigned short)(r >> 16);
}

// edge dtype: int64 iff the 16 sampled high words are all zero (uniform
// scalar loads, evaluated per-block).
__device__ __forceinline__ int edges_are_i64(const unsigned int* raw) {
    int f = 1;
#pragma unroll
    for (int k = 0; k < 16; ++k) f = f && (raw[2 * k + 1] == 0u);
    return f;
}
__device__ __forceinline__ int edge_at(const unsigned int* raw, int f,
                                       size_t idx) {
    return f ? (int)raw[2 * idx] : (int)raw[idx];
}

// ---------------------------------------------------------------------------
// K1: xl = x@W_l+b_l (-> bf16), xr = x@W_r+b_r (-> fp32). (Nx64)@(64x256).
// 16 nodes per 256-thread block; x-tile in LDS; thread j owns column j.
// FUSED: degree histogram appended as a grid-stride tail (one fewer 850K-edge
// dispatch; atomics overlap the FMA phase of other blocks).
// ---------------------------------------------------------------------------
__global__ __launch_bounds__(256) void k_proj(
    const float* __restrict__ x, const float* __restrict__ Wl,
    const float* __restrict__ bl, const float* __restrict__ Wr,
    const float* __restrict__ br, unsigned short* __restrict__ xl,
    float* __restrict__ xr, int N,
    const unsigned int* __restrict__ eraw, int* __restrict__ deg, int E,
    int Etot) {
    __shared__ float xs[64][TM + 4];
    const int tid = threadIdx.x;
    const int base = blockIdx.x * TM;
    for (int t = tid; t < TM * 64; t += 256) {
        int m = t >> 6, k = t & 63;
        int n = base + m;
        xs[k][m] = (n < N) ? x[(size_t)n * 64 + k] : 0.f;
    }
    __syncthreads();
    const int j = tid;  // output column 0..255
    v2f accl2[TM / 2], accr2[TM / 2];
    const float blj = bl[j], brj = br[j];
#pragma unroll
    for (int m = 0; m < TM / 2; ++m) {
        accl2[m].x = blj; accl2[m].y = blj;
        accr2[m].x = brj; accr2[m].y = brj;
    }
    for (int k = 0; k < 64; ++k) {
        const float wl = Wl[(size_t)k * 256 + j];
        const float wr = Wr[(size_t)k * 256 + j];
        v2f wl2, wr2;
        wl2.x = wl; wl2.y = wl;
        wr2.x = wr; wr2.y = wr;
        const float4* xrow = (const float4*)(&xs[k][0]);
#pragma unroll
        for (int mm = 0; mm < TM / 4; ++mm) {
            float4 xv = xrow[mm];
            v2f x01, x23;
            x01.x = xv.x; x01.y = xv.y;
            x23.x = xv.z; x23.y = xv.w;
            accl2[2 * mm]     = __builtin_elementwise_fma(x01, wl2, accl2[2 * mm]);
            accl2[2 * mm + 1] = __builtin_elementwise_fma(x23, wl2, accl2[2 * mm + 1]);
            accr2[2 * mm]     = __builtin_elementwise_fma(x01, wr2, accr2[2 * mm]);
            accr2[2 * mm + 1] = __builtin_elementwise_fma(x23, wr2, accr2[2 * mm + 1]);
        }
    }
#pragma unroll
    for (int m = 0; m < TM; ++m) {
        int n = base + m;
        if (n < N) {
            float vl = (m & 1) ? accl2[m >> 1].y : accl2[m >> 1].x;
            float vr = (m & 1) ? accr2[m >> 1].y : accr2[m >> 1].x;
            xl[(size_t)n * 256 + j] = f2b(vl);
            xr[(size_t)n * 256 + j] = vr;
        }
    }
    // fused histogram tail
    const int f = edges_are_i64(eraw);
    const int stride = gridDim.x * 256;
    for (int e = blockIdx.x * 256 + tid; e < Etot; e += stride) {
        int d = (e < E) ? edge_at(eraw, f, (size_t)E + e) : (e - E);
        if ((unsigned)d >= (unsigned)N) d = 0;  // defensive clamp
        atomicAdd(&deg[d], 1);
    }
}

// ---------------------------------------------------------------------------
// CSR build: parallel 2-kernel scan (196 blocks each) -> scatter via cursor.
// (r11 lesson: single-block scan = 109us serial bottleneck; r13 lesson:
// single-ticket work queue = ~650us same-address atomic serialization.)
// ---------------------------------------------------------------------------
__global__ void k_scanA(const int* __restrict__ deg, int* __restrict__ bsum,
                        int N) {
    __shared__ int s[256];
    int t = threadIdx.x;
    int i = blockIdx.x * 256 + t;
    s[t] = (i < N) ? deg[i] : 0;
    __syncthreads();
    for (int d = 128; d > 0; d >>= 1) {
        if (t < d) s[t] += s[t + d];
        __syncthreads();
    }
    if (t == 0) bsum[blockIdx.x] = s[0];
}

// fused: each block computes its global offset (masked reduce over bsum,
// NB <= 256) then the exclusive scan of its own 256 deg entries.
// Writes BOTH row_start and cursor (scatter consumes cursor atomically).
__global__ void k_scanC(const int* __restrict__ deg,
                        const int* __restrict__ bsum,
                        int* __restrict__ row_start, int* __restrict__ cursor,
                        int Etot, int N) {
    __shared__ int s[256];
    __shared__ int off_s;
    const int t = threadIdx.x;
    s[t] = (t < blockIdx.x) ? bsum[t] : 0;
    __syncthreads();
    for (int d = 128; d > 0; d >>= 1) {
        if (t < d) s[t] += s[t + d];
        __syncthreads();
    }
    if (t == 0) off_s = s[0];
    __syncthreads();
    const int offset = off_s;
    __syncthreads();
    const int i = blockIdx.x * 256 + t;
    const int v = (i < N) ? deg[i] : 0;
    s[t] = v;
    __syncthreads();
    for (int d = 1; d < 256; d <<= 1) {
        int add = (t >= d) ? s[t - d] : 0;
        __syncthreads();
        s[t] += add;
        __syncthreads();
    }
    if (i < N) {
        int rs = s[t] - v + offset;
        row_start[i] = rs;
        cursor[i] = rs;
    }
    if (blockIdx.x == gridDim.x - 1 && t == 0) row_start[N] = Etot;
}

__global__ void k_scatter(const unsigned int* __restrict__ raw,
                          int* __restrict__ cursor, int* __restrict__ csr_src,
                          int E, int Etot, int N) {
    int e = blockIdx.x * 256 + threadIdx.x;
    if (e >= Etot) return;
    int f = edges_are_i64(raw);
    int s, d;
    if (e < E) {
        s = edge_at(raw, f, (size_t)e);
        d = edge_at(raw, f, (size_t)E + e);
    } else {
        s = d = e - E;
    }
    if ((unsigned)s >= (unsigned)N) s = 0;  // defensive clamp
    if ((unsigned)d >= (unsigned)N) d = 0;
    int slot = atomicAdd(&cursor[d], 1);
    if ((unsigned)slot < (unsigned)Etot) csr_src[slot] = s;
    // slots are a permutation of [0,Etot): every slot written, value < N.
}

// ---------------------------------------------------------------------------
// K3: per-node softmax-aggregate (r12-proven version, 71us). One wave per
// node, STATIC mapping (blockIdx*4+wave). Two edges per pass (half = lane>>5;
// sub-lane owns 8 channels of one head; uint4 bf16 gather), rotating D=3
// pipeline, packed-float2 channel math. Near its instruction floor:
// measured 67M wave-inst vs ~60M static (incl. ~15% tail waste).
// ---------------------------------------------------------------------------
__global__ __launch_bounds__(256) void k_aggregate(
    const unsigned short* __restrict__ xl, const float* __restrict__ xr,
    const float* __restrict__ att, const float* __restrict__ bias,
    const int* __restrict__ row_start, const int* __restrict__ csr_src,
    float* __restrict__ out, int N) {
    const int wave = threadIdx.x >> 6;
    const int lane = threadIdx.x & 63;
    const int i = blockIdx.x * 4 + wave;
    if (i >= N) return;
    const int half = lane >> 5;  // which edge of the pair
    const int sl = lane & 31;    // channels [sl*8, sl*8+8) of the 256-row
    const int co = sl * 8;

    v2f xrv[4], av[4];
    {
        const float4 x0 = *(const float4*)(xr + (size_t)i * 256 + co);
        const float4 x1 = *(const float4*)(xr + (size_t)i * 256 + co + 4);
        xrv[0].x = x0.x; xrv[0].y = x0.y;
        xrv[1].x = x0.z; xrv[1].y = x0.w;
        xrv[2].x = x1.x; xrv[2].y = x1.y;
        xrv[3].x = x1.z; xrv[3].y = x1.w;
        const float4 a0 = *(const float4*)(att + co);
        const float4 a1 = *(const float4*)(att + co + 4);
        av[0].x = a0.x; av[0].y = a0.y;
        av[1].x = a0.z; av[1].y = a0.w;
        av[2].x = a1.x; av[2].y = a1.y;
        av[3].x = a1.z; av[3].y = a1.w;
    }
    v2f accv[4];
#pragma unroll
    for (int p = 0; p < 4; ++p) { accv[p].x = 0.f; accv[p].y = 0.f; }
    float den = 0.f;
    const int beg = row_start[i];
    const int end = row_start[i + 1];  // deg >= 1 (self loop)
    const int last = end - 1;
    const unsigned short* xlo = xl + co;  // lane-constant base

    constexpr int D = 3;  // pair-slots in flight (6 edges)
    uint4 cur[D];
    int sidx[D];
#pragma unroll
    for (int d = 0; d < D; ++d) {
        int s = csr_src[min(beg + 2 * d + half, last)];
        cur[d] = *(const uint4*)(xlo + (size_t)s * 256);
    }
#pragma unroll
    for (int d = 0; d < D; ++d)
        sidx[d] = csr_src[min(beg + 2 * D + 2 * d + half, last)];

    for (int e = beg; e < end; e += 2 * D) {
#pragma unroll
        for (int d = 0; d < D; ++d) {
            const uint4 cu = cur[d];
            // rotate: refill this slot for edge e+2D+2d+half
            cur[d] = *(const uint4*)(xlo + (size_t)sidx[d] * 256);
            sidx[d] = csr_src[min(e + 4 * D + 2 * d + half, last)];

            v2f c0 = unpack2(cu.x), c1 = unpack2(cu.y);
            v2f c2 = unpack2(cu.z), c3 = unpack2(cu.w);
            v2f v0 = c0 + xrv[0], v1 = c1 + xrv[1];
            v2f v2 = c2 + xrv[2], v3 = c3 + xrv[3];
            v0 = __builtin_elementwise_max(v0, v0 * 0.2f);  // leaky relu
            v1 = __builtin_elementwise_max(v1, v1 * 0.2f);
            v2 = __builtin_elementwise_max(v2, v2 * 0.2f);
            v3 = __builtin_elementwise_max(v3, v3 * 0.2f);
            v2f t2a = av[0] * v0;
            v2f t2b = av[1] * v1;
            t2a = __builtin_elementwise_fma(av[2], v2, t2a);
            t2b = __builtin_elementwise_fma(av[3], v3, t2b);
            t2a += t2b;
            float t = t2a.x + t2a.y;
            t += __shfl_xor(t, 1);
            t += __shfl_xor(t, 2);
            t += __shfl_xor(t, 4);  // head dot complete (8 lanes/head)
            float w = __expf(fminf(t, 60.f));
            w = (e + 2 * d + half <= last) ? w : 0.f;  // tail mask
            den += w;
            v2f w2;
            w2.x = w; w2.y = w;
            accv[0] = __builtin_elementwise_fma(w2, c0, accv[0]);
            accv[1] = __builtin_elementwise_fma(w2, c1, accv[1]);
            accv[2] = __builtin_elementwise_fma(w2, c2, accv[2]);
            accv[3] = __builtin_elementwise_fma(w2, c3, accv[3]);
        }
    }
    // combine the two edge-parity halves
    den += __shfl_xor(den, 32);
    float r[8];
    r[0] = accv[0].x; r[1] = accv[0].y; r[2] = accv[1].x; r[3] = accv[1].y;
    r[4] = accv[2].x; r[5] = accv[2].y; r[6] = accv[3].x; r[7] = accv[3].y;
#pragma unroll
    for (int j = 0; j < 8; ++j) r[j] += __shfl_xor(r[j], 32);
    const float inv = 1.f / den;
#pragma unroll
    for (int j = 0; j < 8; ++j) r[j] *= inv;
    // mean over heads: heads occupy sub-lane groups of 8
#pragma unroll
    for (int j = 0; j < 8; ++j) {
        r[j] += __shfl_xor(r[j], 8);
        r[j] += __shfl_xor(r[j], 16);
    }
    if (lane < 8) {
        const float4 b0 = *(const float4*)(bias + lane * 8);
        const float4 b1 = *(const float4*)(bias + lane * 8 + 4);
        *(float4*)(out + (size_t)i * 64 + lane * 8) =
            make_float4(b0.x + 0.25f * r[0], b0.y + 0.25f * r[1],
                        b0.z + 0.25f * r[2], b0.w + 0.25f * r[3]);
        *(float4*)(out + (size_t)i * 64 + lane * 8 + 4) =
            make_float4(b1.x + 0.25f * r[4], b1.y + 0.25f * r[5],
                        b1.z + 0.25f * r[6], b1.w + 0.25f * r[7]);
    }
}

// ---------------------------------------------------------------------------
extern "C" void kernel_launch(void* const* d_in, const int* in_sizes, int n_in,
                              void* d_out, int out_size, void* d_ws,
                              size_t ws_size, hipStream_t stream) {
    const float* x    = (const float*)d_in[0];
    const float* Wl   = (const float*)d_in[1];
    const float* bl   = (const float*)d_in[2];
    const float* Wr   = (const float*)d_in[3];
    const float* br   = (const float*)d_in[4];
    const float* att  = (const float*)d_in[5];
    const float* bias = (const float*)d_in[6];
    const unsigned int* edges_raw = (const unsigned int*)d_in[7];

    const int N = in_sizes[0] / 64;
    const int E = in_sizes[7] / 2;
    const int Etot = E + N;

    // workspace layout (~81 MB; evidenced safe r2/r5/r7-r13)
    char* p = (char*)d_ws;
    size_t off = 0;
    auto carve = [&](size_t bytes) -> char* {
        char* r = p + off;
        off = (off + bytes + 255) & ~(size_t)255;
        return r;
    };
    unsigned short* xl = (unsigned short*)carve((size_t)N * 256 * 2);  // 25.6 MB
    float* xr      = (float*)carve((size_t)N * 256 * 4);               // 51.2 MB
    int* csr_src   = (int*)carve((size_t)Etot * 4);                    // 3.4 MB
    int* row_start = (int*)carve((size_t)(N + 1) * 4);
    int* deg       = (int*)carve((size_t)N * 4);
    int* cursor    = (int*)carve((size_t)N * 4);  // fully written by scanC
    int* bsum      = (int*)carve(1024 * 4);

    hipMemsetAsync(deg, 0, (size_t)N * 4, stream);

    k_proj<<<(N + TM - 1) / TM, 256, 0, stream>>>(x, Wl, bl, Wr, br, xl, xr, N,
                                                  edges_raw, deg, E, Etot);
    const int NB = (N + 255) / 256;  // 196 <= 256: bsum prefix fits one block
    k_scanA<<<NB, 256, 0, stream>>>(deg, bsum, N);
    k_scanC<<<NB, 256, 0, stream>>>(deg, bsum, row_start, cursor, Etot, N);
    k_scatter<<<(Etot + 255) / 256, 256, 0, stream>>>(edges_raw, cursor,
                                                      csr_src, E, Etot, N);
    k_aggregate<<<(N + 3) / 4, 256, 0, stream>>>(xl, xr, att, bias, row_start,
                                                 csr_src, (float*)d_out, N);
}